// Round 9
// baseline (275.793 us; speedup 1.0000x reference)
//
#include <hip/hip_runtime.h>

#define Bb 16
#define Ll 2048
#define Hh 768
#define Dd 64
#define Cc 64
#define HC 64             // scan h-tile width (256 B rows -> full-line stores)
#define NT (Hh / HC)      // 12 h-tiles
#define NCH (Ll / Cc)     // 32 chunks
#define TG 4              // scan: tiles per block
#define NTG (NT / TG)     // 3 tile-groups
#define HCs 32            // stateprefix h-slice width
#define NHS (Hh / HCs)    // 24 h-slices

typedef __attribute__((ext_vector_type(8))) short bf16x8;
typedef __attribute__((ext_vector_type(4))) float f32x4;

__device__ __forceinline__ short f2bf(float f) {
  union { float f; unsigned u; } c;
  c.f = f;
  unsigned r = (c.u + 0x7FFFu + ((c.u >> 16) & 1u)) >> 16;
  return (short)r;
}
__device__ __forceinline__ unsigned pack2(float a, float b) {
  return (unsigned)(unsigned short)f2bf(a) | ((unsigned)(unsigned short)f2bf(b) << 16);
}

// CK-style barrier: waits LDS ops only; global prefetch loads stay in flight.
__device__ __forceinline__ void sync_lds() {
  asm volatile("s_waitcnt lgkmcnt(0)\n\ts_barrier" ::: "memory");
}

// ---------------- Prep (256 thr): per (b,chunk) -> bf16 E, FT, scT (frag layouts) ----------------
// Phase-1 only (no bx): gather E; F = E@w; FT[e][i]; scT masked. Verified structure (R2).
__global__ __launch_bounds__(256) void prep_kernel(const int* __restrict__ x,
                                                   const float* __restrict__ ae,
                                                   const float* __restrict__ w,
                                                   short* __restrict__ Eg,
                                                   short* __restrict__ FTg,
                                                   short* __restrict__ scTg) {
  const int tid = threadIdx.x;
  const int wv = tid >> 6, lane = tid & 63, quad = lane >> 4, lq = lane & 15;
  const int b = blockIdx.x >> 5, ch = blockIdx.x & 31;
  const size_t gb = (size_t)blockIdx.x * 4096;
  __shared__ short sE[64 * 64];   // rows i, cols d (swizzled)
  __shared__ short sWT[64 * 64];  // rows e, cols d (swizzled) = w^T
  __shared__ short sF[64 * 64];   // rows i, cols e (swizzled)

  // gather E rows -> sE + Eg;  stage w^T
  {
    const int i = tid >> 2, seg = tid & 3;
    const int idx = x[b * Ll + ch * Cc + i];
    const float4* aer = (const float4*)(ae + (size_t)idx * Dd) + seg * 4;
    float4 ev[4];
#pragma unroll
    for (int q = 0; q < 4; ++q) ev[q] = aer[q];
    uint4 pA, pB;
    pA.x = pack2(ev[0].x, ev[0].y); pA.y = pack2(ev[0].z, ev[0].w);
    pA.z = pack2(ev[1].x, ev[1].y); pA.w = pack2(ev[1].z, ev[1].w);
    pB.x = pack2(ev[2].x, ev[2].y); pB.y = pack2(ev[2].z, ev[2].w);
    pB.z = pack2(ev[3].x, ev[3].y); pB.w = pack2(ev[3].z, ev[3].w);
    *(uint4*)&sE[i * 64 + (((2 * seg) ^ (i & 7)) << 3)] = pA;
    *(uint4*)&sE[i * 64 + (((2 * seg + 1) ^ (i & 7)) << 3)] = pB;
    *(uint4*)(Eg + gb + i * 64 + seg * 16) = pA;
    *(uint4*)(Eg + gb + i * 64 + seg * 16 + 8) = pB;
    const float4* wr = (const float4*)w;
#pragma unroll
    for (int q = 0; q < 4; ++q) {
      const int fl = q * 256 + tid;
      const int d = fl >> 4, es = (fl & 15) * 4;
      const float4 v = wr[fl];
      const float vv[4] = {v.x, v.y, v.z, v.w};
#pragma unroll
      for (int c = 0; c < 4; ++c) {
        const int e = es + c;
        sWT[e * 64 + (((d >> 3) ^ (e & 7)) << 3) + (d & 7)] = f2bf(vv[c]);
      }
    }
  }
  __syncthreads();

  const int rm = wv * 16 + lq;
  bf16x8 aE[2], aW[2];
#pragma unroll
  for (int ks = 0; ks < 2; ++ks) {
    const int blk = ((ks * 4 + quad) ^ (rm & 7)) << 3;
    aE[ks] = *(const bf16x8*)&sE[rm * 64 + blk];
    aW[ks] = *(const bf16x8*)&sWT[rm * 64 + blk];
  }

  // F[i][e] = sum_d E[i][d] w[d][e] -> sF ;  FT[e][i] -> FTg (linear frag layout)
#pragma unroll
  for (int nt = 0; nt < 4; ++nt) {
    const int rn = nt * 16 + lq;
    f32x4 accF = {}, accT = {};
#pragma unroll
    for (int ks = 0; ks < 2; ++ks) {
      const int blk = ((ks * 4 + quad) ^ (rn & 7)) << 3;
      const bf16x8 bW = *(const bf16x8*)&sWT[rn * 64 + blk];
      const bf16x8 bE = *(const bf16x8*)&sE[rn * 64 + blk];
      accF = __builtin_amdgcn_mfma_f32_16x16x32_bf16(aE[ks], bW, accF, 0, 0, 0);
      accT = __builtin_amdgcn_mfma_f32_16x16x32_bf16(aW[ks], bE, accT, 0, 0, 0);
    }
#pragma unroll
    for (int r = 0; r < 4; ++r) {
      const int i = wv * 16 + quad * 4 + r;   // m of accF
      const int e = nt * 16 + lq;
      sF[i * 64 + (((e >> 3) ^ (i & 7)) << 3) + (e & 7)] = f2bf(accF[r]);
      const int e2 = wv * 16 + quad * 4 + r;  // m of accT
      const int i2 = nt * 16 + lq;
      FTg[gb + e2 * 64 + i2] = f2bf(accT[r]);
    }
  }
  __syncthreads();

  // sc[j][i] = sum_e E[j][e] F[i][e], strict mask i<j -> scTg rows j
#pragma unroll
  for (int nt = 0; nt < 4; ++nt) {
    const int rn = nt * 16 + lq;
    f32x4 acc = {};
#pragma unroll
    for (int ks = 0; ks < 2; ++ks) {
      const int blk = ((ks * 4 + quad) ^ (rn & 7)) << 3;
      const bf16x8 bF = *(const bf16x8*)&sF[rn * 64 + blk];
      acc = __builtin_amdgcn_mfma_f32_16x16x32_bf16(aE[ks], bF, acc, 0, 0, 0);
    }
#pragma unroll
    for (int r = 0; r < 4; ++r) {
      const int j = wv * 16 + quad * 4 + r;
      const int i = nt * 16 + lq;
      scTg[gb + j * 64 + i] = f2bf(i < j ? acc[r] : 0.f);
    }
  }
}

// ---------------- StatePrefix (256 thr): per (h-slice, b) — fused state + exclusive prefix ----------------
// For its 32 h-rows, loops ch=0..31: STg[b,ch][h,e] = f32-prefix BEFORE chunk ch;
// acc[h,e] += sum_i (i+1)*bx[i,h]*F[i,e] via MFMA (C-operand IS the running prefix).
// id = ht*16 + b -> all 24 slices of one b share an XCD (FTg L2 locality).
__global__ __launch_bounds__(256) void stateprefix_kernel(const float* __restrict__ bx,
                                                          const short* __restrict__ FTg,
                                                          short* __restrict__ STg) {
  const int id = blockIdx.x;
  const int b = id & 15, ht = id >> 4;     // ht 0..23
  const int tid = threadIdx.x;
  const int wv = tid >> 6, lane = tid & 63, quad = lane >> 4, lq = lane & 15;
  const int mh = wv >> 1, nh = wv & 1;     // 4 waves: 2 m(h)-tiles x 2 n(e)-halves
  const int ip = tid & 31, hg = tid >> 5;  // staging: i-pair 0..31, h-group 0..7 (4 h each)
  const int rm = mh * 16 + lq;

  __shared__ short sGT[2][HCs * 64];       // G^T rows h(local 0..31), cols i (swizzled), dbuf

  f32x4 acc[2] = {};                       // f32 prefix state: this wave's 2 e-tiles
  float4 rGa, rGb;
  auto load_G = [&](int ch) {
    const float* xr = bx + ((size_t)(b * Ll) + ch * Cc + 2 * ip) * Hh + ht * HCs + hg * 4;
    rGa = *(const float4*)xr;              // i = 2*ip
    rGb = *(const float4*)(xr + Hh);       // i = 2*ip+1
  };
  load_G(0);

  for (int ch = 0; ch < NCH; ++ch) {
    const size_t gb = (size_t)(b * NCH + ch) * 4096;
    // FT frags for this chunk (issued early; consumed after barrier; L2-resident)
    bf16x8 bD[2][2];
#pragma unroll
    for (int t = 0; t < 2; ++t) {
      const int rn = (nh * 2 + t) * 16 + lq;
#pragma unroll
      for (int ks = 0; ks < 2; ++ks)
        bD[t][ks] = *(const bf16x8*)(FTg + gb + rn * 64 + (ks * 4 + quad) * 8);
    }
    short* gbuf = sGT[ch & 1];
    // stage scaled G^T for this chunk
    {
      const float s0 = (float)(ch * Cc + 2 * ip + 1), s1 = s0 + 1.0f;
      const float A[4] = {rGa.x, rGa.y, rGa.z, rGa.w};
      const float Bv[4] = {rGb.x, rGb.y, rGb.z, rGb.w};
#pragma unroll
      for (int e = 0; e < 4; ++e) {
        const int hl = hg * 4 + e;   // 0..31
        const int sa = hl * 64 + (((ip >> 2) ^ (hl & 7)) << 3) + 2 * (ip & 3);
        *(unsigned*)&gbuf[sa] = pack2(A[e] * s0, Bv[e] * s1);
      }
    }
    if (ch + 1 < NCH) load_G(ch + 1);      // next chunk's G in flight across barrier
    sync_lds();                             // lgkm-only

    // store EXCLUSIVE prefix (state before this chunk), bf16
    short* So = STg + (size_t)(b * NCH + ch) * (Hh * Dd);
#pragma unroll
    for (int t = 0; t < 2; ++t)
#pragma unroll
      for (int r = 0; r < 4; ++r) {
        const int h = ht * HCs + mh * 16 + quad * 4 + r;
        So[h * 64 + (nh * 2 + t) * 16 + lq] = f2bf(acc[t][r]);
      }

    // accumulate this chunk into the f32 prefix
    bf16x8 aG[2];
#pragma unroll
    for (int ks = 0; ks < 2; ++ks)
      aG[ks] = *(const bf16x8*)&gbuf[rm * 64 + (((ks * 4 + quad) ^ (rm & 7)) << 3)];
#pragma unroll
    for (int t = 0; t < 2; ++t)
#pragma unroll
      for (int ks = 0; ks < 2; ++ks)
        acc[t] = __builtin_amdgcn_mfma_f32_16x16x32_bf16(aG[ks], bD[t][ks], acc[t], 0, 0, 0);
  }
}

// ---------------- Scan: per (tile-group, b, ch) — 4 pipelined h-tiles sharing frags ----------------
// out[j,h] = bx[j,h] + (1/(j+1)) * [ sum_{i<j in ch} sc[j,i]*G[i,h]  +  sum_e E[j,e]*Sprefix[h,e] ]
__global__ __launch_bounds__(256) void scan_kernel(const float* __restrict__ bx,
                                                   const short* __restrict__ Eg,
                                                   const short* __restrict__ scTg,
                                                   const short* __restrict__ STg,
                                                   float* __restrict__ out) {
  const int s = blockIdx.x;             // [0, 3*512): bc%8 fixes XCD for all 3 tile-groups of a bc
  const int tg = s >> 9;                // tile-group 0..2
  const int bc = s & 511;               // (b,ch)
  const int b = bc >> 5, ch = bc & 31;
  const int tid = threadIdx.x;
  const int w = tid >> 6, lane = tid & 63, quad = lane >> 4, lq = lane & 15;
  const int ip = tid & 31, hg = tid >> 5;
  const int rj = w * 16 + lq;

  __shared__ short sGT[2][64 * 64];  // G^T rows h(local), cols i (swizzled), double-buffered

  // loop-invariant fragments: scT rows j (k=i), E rows j (k=e) — loaded ONCE per block
  bf16x8 aC1[2], aC2[2];
  {
    const size_t tb = (size_t)bc * 4096;
#pragma unroll
    for (int ks = 0; ks < 2; ++ks) {
      const int o = rj * 64 + (ks * 4 + quad) * 8;
      aC1[ks] = *(const bf16x8*)(scTg + tb + o);
      aC2[ks] = *(const bf16x8*)(Eg + tb + o);
    }
  }
  const short* Sp = STg + (size_t)bc * (Hh * Dd);

  float4 rGa[2], rGb[2];
  bf16x8 stF[4][2];
  auto load_G = [&](int tl) {
    const float* xr = bx + ((size_t)(b * Ll) + ch * Cc + 2 * ip) * Hh + tl * HC + hg * 8;
    rGa[0] = *(const float4*)(xr);
    rGa[1] = *(const float4*)(xr + 4);
    rGb[0] = *(const float4*)(xr + Hh);
    rGb[1] = *(const float4*)(xr + Hh + 4);
  };
  auto load_S = [&](int tl) {
#pragma unroll
    for (int ht = 0; ht < 4; ++ht) {
      const int h = tl * HC + ht * 16 + lq;
#pragma unroll
      for (int ks = 0; ks < 2; ++ks)
        stF[ht][ks] = *(const bf16x8*)(Sp + h * 64 + (ks * 4 + quad) * 8);
    }
  };

  load_G(tg * TG);
  load_S(tg * TG);

  const float s0 = (float)(ch * Cc + 2 * ip + 1), s1 = (float)(ch * Cc + 2 * ip + 2);

#pragma unroll
  for (int t = 0; t < TG; ++t) {
    const int tl = tg * TG + t;
    short* gbuf = sGT[t & 1];
    // stage G^T (scaled bx, h x i) from regs into LDS
    {
      const float A[8] = {rGa[0].x, rGa[0].y, rGa[0].z, rGa[0].w,
                          rGa[1].x, rGa[1].y, rGa[1].z, rGa[1].w};
      const float Bv[8] = {rGb[0].x, rGb[0].y, rGb[0].z, rGb[0].w,
                           rGb[1].x, rGb[1].y, rGb[1].z, rGb[1].w};
#pragma unroll
      for (int e = 0; e < 8; ++e) {
        const int hl = hg * 8 + e;
        const int sa = hl * 64 + (((ip >> 2) ^ (hl & 7)) << 3) + 2 * (ip & 3);
        *(unsigned*)&gbuf[sa] = pack2(A[e] * s0, Bv[e] * s1);
      }
    }
    if (t + 1 < TG) load_G(tl + 1);   // next tile's G in flight across the barrier
    sync_lds();                        // lgkm-only: global loads keep flying

#pragma unroll
    for (int ht = 0; ht < 4; ++ht) {
      const int rh = ht * 16 + lq;
      f32x4 accO = {};
#pragma unroll
      for (int ks = 0; ks < 2; ++ks) {
        const int blk = ((ks * 4 + quad) ^ (rh & 7)) << 3;
        const bf16x8 gv = *(const bf16x8*)&gbuf[rh * 64 + blk];
        accO = __builtin_amdgcn_mfma_f32_16x16x32_bf16(aC1[ks], gv, accO, 0, 0, 0);
        accO = __builtin_amdgcn_mfma_f32_16x16x32_bf16(aC2[ks], stF[ht][ks], accO, 0, 0, 0);
      }
#pragma unroll
      for (int r = 0; r < 4; ++r) {
        const int gj = ch * Cc + w * 16 + quad * 4 + r;
        const size_t off = ((size_t)(b * Ll) + gj) * Hh + tl * HC + ht * 16 + lq;
        out[off] = bx[off] + accO[r] * (1.0f / (float)(gj + 1));
      }
    }
    if (t + 1 < TG) load_S(tl + 1);   // stF regs free after MFMAs above
  }
}

extern "C" void kernel_launch(void* const* d_in, const int* in_sizes, int n_in,
                              void* d_out, int out_size, void* d_ws, size_t ws_size,
                              hipStream_t stream) {
  (void)in_sizes; (void)n_in; (void)out_size; (void)ws_size;
  const float* bx = (const float*)d_in[0];
  const int* x = (const int*)d_in[1];
  const float* ae = (const float*)d_in[2];
  const float* w = (const float*)d_in[3];
  float* out = (float*)d_out;
  short* Eg = (short*)d_ws;                        // 512*4096 bf16 = 4 MB
  short* FTg = Eg + (size_t)512 * 4096;            // 4 MB
  short* scTg = FTg + (size_t)512 * 4096;          // 4 MB
  short* STg = scTg + (size_t)512 * 4096;          // 512*768*64 bf16 = 50.3 MB (exclusive prefixes)

  prep_kernel<<<Bb * NCH, 256, 0, stream>>>(x, ae, w, Eg, FTg, scTg);
  stateprefix_kernel<<<NHS * Bb, 256, 0, stream>>>(bx, FTg, STg);
  scan_kernel<<<NTG * Bb * NCH, 256, 0, stream>>>(bx, Eg, scTg, STg, out);
}